// Round 4
// baseline (493.391 us; speedup 1.0000x reference)
//
#include <hip/hip_runtime.h>
#include <math.h>

#define MM 4
#define BB 128
#define CC 10
#define KK 32
#define FF 512
#define HH 512
#define NP 320            // C*K rows per model
#define K1P 544           // padded k for fc1 (512 noise + 10 onehot + 22 zero)
#define OUTW 5120         // F*C
#define GRID 512

using bf16x8 = __attribute__((ext_vector_type(8))) short;
using f32x4  = __attribute__((ext_vector_type(4))) float;

__device__ __forceinline__ unsigned short f2bf(float f) {
    unsigned int u = __float_as_uint(f);
    u += 0x7FFFu + ((u >> 16) & 1u);          // round-to-nearest-even
    return (unsigned short)(u >> 16);
}

// -------- device-wide ticket barrier (counters zeroed per call via memset) --------
__device__ __forceinline__ void gbar(unsigned int* cnt, int i) {
    __syncthreads();
    if (threadIdx.x == 0) {
        __threadfence();
        __hip_atomic_fetch_add(&cnt[i], 1u, __ATOMIC_RELEASE, __HIP_MEMORY_SCOPE_AGENT);
        while (__hip_atomic_load(&cnt[i], __ATOMIC_ACQUIRE, __HIP_MEMORY_SCOPE_AGENT) < (unsigned)GRID)
            __builtin_amdgcn_s_sleep(2);
        __threadfence();
    }
    __syncthreads();
}

// -------- prep unit (one old k_prep block's worth of work) --------
__device__ void prep_unit(int b,
    const float* __restrict__ W1, const float* __restrict__ W2,
    const float* __restrict__ W_lw, const float* __restrict__ noise,
    const float* __restrict__ r1, const float* __restrict__ x,
    const float* __restrict__ r_lw, const float* __restrict__ s_lw,
    unsigned short* __restrict__ W1t, unsigned short* __restrict__ W2t,
    unsigned short* __restrict__ Wlwt, unsigned short* __restrict__ A1,
    unsigned short* __restrict__ xr, float* __restrict__ s_r,
    float* __restrict__ dist, float* __restrict__ pn,
    unsigned short* smem)
{
    const int t = threadIdx.x;
    if (b < 776) {
        unsigned short (*T)[65] = (unsigned short (*)[65])smem;
        const float* W; unsigned short* Wt; int K, N, Kp, nt, kt; bool remap = false;
        if (b < 72)       { W = W1;   Wt = W1t;  K = 522; N = 512;  Kp = 544; nt = b % 8;          kt = b / 8; }
        else if (b < 136) { int bb = b - 72;  W = W2;   Wt = W2t;  K = 512; N = 512;  Kp = 512; nt = bb % 8;  kt = bb / 8; }
        else              { int bb = b - 136; W = W_lw; Wt = Wlwt; K = 512; N = 5120; Kp = 512; nt = bb % 80; kt = bb / 80; remap = true; }
        const int n0 = nt * 64, k0 = kt * 64;
#pragma unroll
        for (int p = 0; p < 4; ++p) {
            int kk = (t >> 4) + p * 16;
            int nn = (t & 15) * 4;
            int gk = k0 + kk;
            float4 v = {0.f, 0.f, 0.f, 0.f};
            if (gk < K) v = *(const float4*)(W + (size_t)gk * N + n0 + nn);
            T[nn + 0][kk] = f2bf(v.x);
            T[nn + 1][kk] = f2bf(v.y);
            T[nn + 2][kk] = f2bf(v.z);
            T[nn + 3][kk] = f2bf(v.w);
        }
        __syncthreads();
#pragma unroll
        for (int p = 0; p < 2; ++p) {
            int n  = (t >> 3) + p * 32;
            int kg = t & 7;
            int gk = k0 + kg * 8;
            if (gk < Kp) {
                union { unsigned short u[8]; uint4 v; } o;
#pragma unroll
                for (int q = 0; q < 8; ++q) o.u[q] = T[n][kg * 8 + q];
                int gn = n0 + n;
                int dr = remap ? ((gn % 10) * 512 + gn / 10) : gn;
                *(uint4*)(Wt + (size_t)dr * Kp + gk) = o.v;
            }
        }
    } else if (b < 1116) {
        const int id = (b - 776) * 256 + t;          // 1280*68 = 87040 exact
        const int row = id / 68, g = id % 68;
        const int m = row / NP, n = row % NP;
        union { unsigned short u[8]; uint4 v; } o;
        if (g < 64) {
            const float* npnt = noise + (size_t)n * 512 + g * 8;
            const float* rp = r1 + (size_t)m * 522 + g * 8;
#pragma unroll
            for (int q = 0; q < 8; ++q) o.u[q] = f2bf(npnt[q] * rp[q]);
        } else {
            const int colbase = 512 + (g - 64) * 8;
            const int cn = n >> 5;
#pragma unroll
            for (int q = 0; q < 8; ++q) {
                int col = colbase + q;
                float v = (col - 512 == cn) ? r1[(size_t)m * 522 + col] : 0.f;
                o.u[q] = f2bf(v);
            }
        }
        *(uint4*)(A1 + (size_t)row * K1P + g * 8) = o.v;
    } else if (b < 1244) {
        const int id = (b - 1116) * 256 + t;         // 512*64 = 32768 exact
        const int row = id >> 6, g = id & 63;
        const int m = row >> 7;
        const float* xp = x + (size_t)row * 512 + g * 8;
        const float* rp = r_lw + (size_t)m * 512 + g * 8;
        union { unsigned short u[8]; uint4 v; } o;
#pragma unroll
        for (int q = 0; q < 8; ++q) o.u[q] = f2bf(xp[q] * rp[q]);
        *(uint4*)(xr + (size_t)row * 512 + g * 8) = o.v;
    } else {
        const int id = (b - 1244) * 256 + t;         // 30760 work items
        if (id < 20480) {
            const int m = id / 5120, d = id % 5120;  // d = c*512+f
            s_r[id] = s_lw[(size_t)m * 5120 + (d % 512) * 10 + d / 512];
        } else if (id < 30720) {
            dist[id - 20480] = 0.f;
        } else if (id < 30760) {
            pn[id - 30720] = 0.f;
        }
    }
}

// -------- MFMA GEMM tile, templated epilogue --------
// EPI 0: outv = bf16( relu(acc*s + bias) * auxr )                (fc1 -> A2)
// EPI 1: psum/pn fused reduce (I==2): outv=psum write, auxw=pn atomic
// EPI 2: zn/cr fused reduce (I==2,J==4): bias=psum read, outv=dist atomics
template<int EPI, int I, int J, int KD, int RPM, int NCOLS>
__device__ __forceinline__ void gemm_tile(
    const int bx, const int by,
    const unsigned short* __restrict__ A, const unsigned short* __restrict__ Bt,
    const float* __restrict__ s, const float* __restrict__ bias,
    const float* __restrict__ auxr, void* __restrict__ outv,
    float* __restrict__ auxw, unsigned short* smem)
{
    constexpr int TR = 2 * I * 16;
    constexpr int TC = 2 * J * 16;
    constexpr int NUA = TR / 64;
    constexpr int NUB = TC / 64;
    unsigned short* As = smem;             // TR*32 elems
    unsigned short* Bs = smem + TR * 32;   // TC*32 elems
    const int t = threadIdx.x;
    const int lane = t & 63;
    const int w = t >> 6;
    const int wr = w >> 1, wc = w & 1;
    const int l15 = lane & 15, l4 = lane >> 4;
    const int rowT = by * TR;
    const int colT = bx * TC;

    const unsigned short* gAp[NUA]; int stA[NUA];
#pragma unroll
    for (int u = 0; u < NUA; ++u) {
        int e = t + u * 256;
        int srow = e >> 2, g = e & 3;
        gAp[u] = A + (size_t)(rowT + srow) * KD + g * 8;
        stA[u] = srow * 32 + ((g ^ ((srow >> 1) & 3)) * 8);
    }
    const unsigned short* gBp[NUB]; int stB[NUB];
#pragma unroll
    for (int u = 0; u < NUB; ++u) {
        int e = t + u * 256;
        int srow = e >> 2, g = e & 3;
        gBp[u] = Bt + (size_t)(colT + srow) * KD + g * 8;
        stB[u] = srow * 32 + ((g ^ ((srow >> 1) & 3)) * 8);
    }

    int offA[I], offB[J];
#pragma unroll
    for (int i = 0; i < I; ++i) {
        int rA = wr * (I * 16) + i * 16 + l15;
        offA[i] = rA * 32 + ((l4 ^ ((rA >> 1) & 3)) * 8);
    }
#pragma unroll
    for (int j = 0; j < J; ++j) {
        int rB = wc * (J * 16) + j * 16 + l15;
        offB[j] = rB * 32 + ((l4 ^ ((rB >> 1) & 3)) * 8);
    }

    f32x4 acc[I][J];
#pragma unroll
    for (int i = 0; i < I; ++i)
#pragma unroll
        for (int j = 0; j < J; ++j) acc[i][j] = (f32x4){0.f, 0.f, 0.f, 0.f};

#pragma unroll 1
    for (int k0 = 0; k0 < KD; k0 += 32) {
        uint4 va[NUA], vb[NUB];
#pragma unroll
        for (int u = 0; u < NUA; ++u) va[u] = *(const uint4*)(gAp[u] + k0);
#pragma unroll
        for (int u = 0; u < NUB; ++u) vb[u] = *(const uint4*)(gBp[u] + k0);
        __syncthreads();
#pragma unroll
        for (int u = 0; u < NUA; ++u) *(uint4*)(As + stA[u]) = va[u];
#pragma unroll
        for (int u = 0; u < NUB; ++u) *(uint4*)(Bs + stB[u]) = vb[u];
        __syncthreads();
        bf16x8 af[I], bfv[J];
#pragma unroll
        for (int i = 0; i < I; ++i) af[i] = *(const bf16x8*)(As + offA[i]);
#pragma unroll
        for (int j = 0; j < J; ++j) bfv[j] = *(const bf16x8*)(Bs + offB[j]);
#pragma unroll
        for (int i = 0; i < I; ++i)
#pragma unroll
            for (int j = 0; j < J; ++j)
                acc[i][j] = __builtin_amdgcn_mfma_f32_16x16x32_bf16(af[i], bfv[j], acc[i][j], 0, 0, 0);
    }

    if constexpr (EPI == 0) {
        const int m = rowT / RPM;            // tile lies within one model
#pragma unroll
        for (int j = 0; j < J; ++j) {
            const int col = colT + wc * (J * 16) + j * 16 + l15;
            const float sv = s[(size_t)m * NCOLS + col];
            const float bv = bias[(size_t)m * NCOLS + col];
            const float rv = auxr[(size_t)m * NCOLS + col];
#pragma unroll
            for (int i = 0; i < I; ++i)
#pragma unroll
                for (int ir = 0; ir < 4; ++ir) {
                    const int row = rowT + wr * (I * 16) + i * 16 + l4 * 4 + ir;
                    float v = fmaxf(acc[i][j][ir] * sv + bv, 0.f) * rv;
                    ((unsigned short*)outv)[(size_t)row * NCOLS + col] = f2bf(v);
                }
        }
    } else if constexpr (EPI == 1) {
        // wave's 32 rows = one (m,c) class group
        static_assert(I == 2, "EPI1 needs 32-row waves");
        const int grow = rowT + wr * 32;
        const int m = grow / NP;
        const int c = (grow % NP) / KK;
        const int mc = m * CC + c;
        float sq = 0.f;
#pragma unroll
        for (int j = 0; j < J; ++j) {
            const int col = colT + wc * (J * 16) + j * 16 + l15;
            const float sv = s[(size_t)m * NCOLS + col];
            const float bv = bias[(size_t)m * NCOLS + col];
            float cs = 0.f;
#pragma unroll
            for (int i = 0; i < I; ++i)
#pragma unroll
                for (int ir = 0; ir < 4; ++ir) {
                    float v = acc[i][j][ir] * sv + bv;
                    cs += v;
                    sq += v * v;
                }
            cs += __shfl_xor(cs, 16, 64);
            cs += __shfl_xor(cs, 32, 64);
            if (l4 == 0) ((float*)outv)[(size_t)mc * FF + col] = cs;
        }
#pragma unroll
        for (int off = 1; off < 64; off <<= 1) sq += __shfl_xor(sq, off, 64);
        if (lane == 0) atomicAdd(&auxw[mc], sq);
    } else {
        // EPI 2: fused zn/cr; tile spans one model (rows) and one class (cols)
        static_assert(I == 2 && J == 4, "EPI2 expects 64x128 tile");
        const int m = rowT / RPM;            // RPM = 128
        const int cb = colT / FF;            // class of this col tile
        float sv[J], pv[J];
#pragma unroll
        for (int j = 0; j < J; ++j) {
            const int col = colT + wc * (J * 16) + j * 16 + l15;
            sv[j] = s[(size_t)m * NCOLS + col];
            pv[j] = bias[(size_t)m * NCOLS + col];   // psum, (c,f)-ordered
        }
        float* dst = (float*)outv;
#pragma unroll
        for (int i = 0; i < I; ++i)
#pragma unroll
            for (int ir = 0; ir < 4; ++ir) {
                const int row = rowT + wr * (I * 16) + i * 16 + l4 * 4 + ir;
                float znv = 0.f, crv = 0.f;
#pragma unroll
                for (int j = 0; j < J; ++j) {
                    float v = acc[i][j][ir] * sv[j];
                    znv += v * v;
                    crv += v * pv[j];
                }
#pragma unroll
                for (int off = 1; off < 16; off <<= 1) {
                    znv += __shfl_xor(znv, off, 64);
                    crv += __shfl_xor(crv, off, 64);
                }
                if (l15 == 0) {
                    float* dp = dst + ((size_t)row * CC + cb) * 2;
                    atomicAdd(dp + 0, znv);
                    atomicAdd(dp + 1, crv);
                }
            }
    }
}

// =================== the single fused kernel ===================
__global__ __launch_bounds__(256, 2) void k_fused(
    const float* __restrict__ x, const float* __restrict__ noise,
    const float* __restrict__ W_lw, const float* __restrict__ r_lw,
    const float* __restrict__ s_lw, const float* __restrict__ W1,
    const float* __restrict__ r1, const float* __restrict__ s1,
    const float* __restrict__ b1, const float* __restrict__ W2,
    const float* __restrict__ r2, const float* __restrict__ s2,
    const float* __restrict__ b2, float* __restrict__ out,
    char* __restrict__ ws)
{
    __shared__ __align__(16) unsigned short smem[8192];  // 16 KiB
    unsigned int* cnt = (unsigned int*)ws;
    float* psum = (float*)(ws + 256);                    // 81,920
    float* pn   = (float*)(ws + 82176);                  // 160
    float* dist = (float*)(ws + 82432);                  // 40,960
    float* s_r  = (float*)(ws + 123392);                 // 81,920
    unsigned short* A1   = (unsigned short*)(ws + 205312);   // 1,392,640
    unsigned short* W1t  = (unsigned short*)(ws + 1597952);  //   557,056
    unsigned short* W2t  = (unsigned short*)(ws + 2155008);  //   524,288
    unsigned short* A2   = (unsigned short*)(ws + 2679296);  // 1,310,720
    unsigned short* xr   = (unsigned short*)(ws + 3990016);  //   524,288
    unsigned short* Wlwt = (unsigned short*)(ws + 4514304);  // 5,242,880

    const int bid = blockIdx.x;

    // ---- P0: prep (transposes, bf16 conversions, zeroing) ----
    for (int u = bid; u < 1365; u += GRID) {
        prep_unit(u, W1, W2, W_lw, noise, r1, x, r_lw, s_lw,
                  W1t, W2t, Wlwt, A1, xr, s_r, dist, pn, smem);
        __syncthreads();
    }
    gbar(cnt, 0);

    // ---- P1: fc1 GEMM (1280x512, k=544), 160 tiles of 64x64 ----
    if (bid < 160)
        gemm_tile<0, 2, 2, K1P, NP, HH>(bid % 8, bid / 8, A1, W1t, s1, b1, r2,
                                        (void*)A2, nullptr, smem);
    gbar(cnt, 1);

    // ---- P2: fc2 GEMM (1280x512, k=512) + fused psum/pn ----
    if (bid < 160)
        gemm_tile<1, 2, 2, 512, NP, FF>(bid % 8, bid / 8, A2, W2t, s2, b2, nullptr,
                                        (void*)psum, pn, smem);
    gbar(cnt, 2);

    // ---- P3: z GEMM (512x5120, k=512) + fused zn/cr, 320 tiles of 64x128 ----
    if (bid < 320)
        gemm_tile<2, 2, 4, 512, BB, OUTW>(bid % 40, bid / 40, xr, Wlwt, s_r, psum,
                                          nullptr, (void*)dist, nullptr, smem);
    gbar(cnt, 3);

    // ---- P4: logits -> exp ----
    if (bid < 20) {
        const int id = bid * 256 + threadIdx.x;      // 5120 exact
        const int c = id % 10;
        const int m = (id / 10) >> 7;
        const float zn = dist[id * 2], cr = dist[id * 2 + 1];
        const float inv = 1.f / (2.f * (float)KK * (float)FF);
        out[id] = expf(-((float)KK * zn - 2.f * cr + pn[m * 10 + c]) * inv);
    }
}

extern "C" void kernel_launch(void* const* d_in, const int* in_sizes, int n_in,
                              void* d_out, int out_size, void* d_ws, size_t ws_size,
                              hipStream_t stream) {
    const float* x     = (const float*)d_in[0];
    const float* noise = (const float*)d_in[1];
    const float* W_lw  = (const float*)d_in[2];
    const float* r_lw  = (const float*)d_in[3];
    const float* s_lw  = (const float*)d_in[4];
    const float* W1    = (const float*)d_in[5];
    const float* r1    = (const float*)d_in[6];
    const float* s1    = (const float*)d_in[7];
    const float* b1    = (const float*)d_in[8];
    const float* W2    = (const float*)d_in[9];
    const float* r2    = (const float*)d_in[10];
    const float* s2    = (const float*)d_in[11];
    const float* b2    = (const float*)d_in[12];
    float* out = (float*)d_out;

    // zero the barrier counters (replay-safe; captured as a memset node)
    hipMemsetAsync(d_ws, 0, 256, stream);
    k_fused<<<GRID, 256, 0, stream>>>(x, noise, W_lw, r_lw, s_lw,
                                      W1, r1, s1, b1, W2, r2, s2, b2,
                                      out, (char*)d_ws);
}

// Round 5
// 90.255 us; speedup vs baseline: 5.4667x; 5.4667x over previous
//
#include <hip/hip_runtime.h>
#include <math.h>

#define MM 4
#define BB 128
#define CC 10
#define KK 32
#define FF 512
#define HH 512
#define NP 320            // C*K rows per model
#define OUTW 5120         // F*C

using bf16x8 = __attribute__((ext_vector_type(8))) short;
using f32x4  = __attribute__((ext_vector_type(4))) float;

__device__ __forceinline__ unsigned short f2bf(float f) {
    unsigned int u = __float_as_uint(f);
    u += 0x7FFFu + ((u >> 16) & 1u);          // round-to-nearest-even
    return (unsigned short)(u >> 16);
}

// ---------------- unified MFMA GEMM tile ----------------
// EPI 0: outv(u16) = bf16( relu(acc*s + bias) * auxr )          (fc1 -> A2)
// EPI 1: psum direct write (outv) + pn atomic (auxw)            (fc2)
// EPI 2: zn/cr atomics into dist (outv); s indexed (f,c)->(c,f) (z-GEMM)
// ASRC 0: bf16 A[row][512]   (Abf)
// ASRC 1: f32 x[row][512] * ascale[m][512]
// ASRC 2: f32 noise[row%NP][512] * ascale(r1)[m][522], onehot tail k=512..543
// BSRC 0: bf16 Bt[col][512]  (Btbf)
// BSRC 1: f32 W[k][512] direct k-major gather (requires TC==64)
template<int EPI, int ASRC, int BSRC, int I, int J, int KSTEPS, int KREALB,
         int RPM, int NCOLS>
__device__ __forceinline__ void gemm_tile(
    const int bx, const int by,
    const unsigned short* __restrict__ Abf, const float* __restrict__ Af32,
    const float* __restrict__ ascale,
    const unsigned short* __restrict__ Btbf, const float* __restrict__ Bf32,
    const float* __restrict__ s, const float* __restrict__ bias,
    const float* __restrict__ auxr, void* __restrict__ outv,
    float* __restrict__ auxw, unsigned short* smem)
{
    constexpr int TR = 2 * I * 16;
    constexpr int TC = 2 * J * 16;
    constexpr int NUA = TR / 64;
    constexpr int NUB = TC / 64;
    constexpr bool BCHK = (KREALB != KSTEPS * 32);
    unsigned short* As = smem;             // TR*32
    unsigned short* Bs = smem + TR * 32;   // TC*32
    const int t = threadIdx.x;
    const int lane = t & 63;
    const int w = t >> 6, wr = w >> 1, wc = w & 1;
    const int l15 = lane & 15, l4 = lane >> 4;
    const int rowT = by * TR, colT = bx * TC;
    const int m = rowT / RPM;

    // ---- A staging setup ----
    int stA[NUA];
    const unsigned short* gApBf[NUA];
    const float* gApF = nullptr;
    const float* scp = nullptr;
    int arow = 0, ag = 0;
    if constexpr (ASRC == 0) {
#pragma unroll
        for (int u = 0; u < NUA; ++u) {
            int e = t + u * 256;
            int srow = e >> 2, g = e & 3;
            gApBf[u] = Abf + (size_t)(rowT + srow) * 512 + g * 8;
            stA[u] = srow * 32 + ((g ^ ((srow >> 1) & 3)) * 8);
        }
    } else {
        static_assert(NUA == 1, "direct-A needs TR==64");
        arow = t >> 2; ag = t & 3;
        const int grow = (ASRC == 2) ? ((rowT % NP) + arow) : (rowT + arow);
        gApF = Af32 + (size_t)grow * 512 + ag * 8;
        scp = ascale + (size_t)m * ((ASRC == 2) ? 522 : 512) + ag * 8;
        stA[0] = arow * 32 + ((ag ^ ((arow >> 1) & 3)) * 8);
        gApBf[0] = nullptr;
    }
    // ---- B staging setup ----
    int stB[NUB];
    const unsigned short* gBpBf[NUB];
    int bcol = 0, bkg = 0;
    if constexpr (BSRC == 0) {
#pragma unroll
        for (int u = 0; u < NUB; ++u) {
            int e = t + u * 256;
            int srow = e >> 2, g = e & 3;
            gBpBf[u] = Btbf + (size_t)(colT + srow) * 512 + g * 8;
            stB[u] = srow * 32 + ((g ^ ((srow >> 1) & 3)) * 8);
        }
    } else {
        static_assert(NUB == 1, "direct-B needs TC==64");
        bcol = t & 63; bkg = t >> 6;
        stB[0] = bcol * 32 + ((bkg ^ ((bcol >> 1) & 3)) * 8);
        gBpBf[0] = nullptr;
    }

    int offA[I], offB[J];
#pragma unroll
    for (int i = 0; i < I; ++i) {
        int rA = wr * (I * 16) + i * 16 + l15;
        offA[i] = rA * 32 + ((l4 ^ ((rA >> 1) & 3)) * 8);
    }
#pragma unroll
    for (int j = 0; j < J; ++j) {
        int rB = wc * (J * 16) + j * 16 + l15;
        offB[j] = rB * 32 + ((l4 ^ ((rB >> 1) & 3)) * 8);
    }

    f32x4 acc[I][J];
#pragma unroll
    for (int i = 0; i < I; ++i)
#pragma unroll
        for (int j = 0; j < J; ++j) acc[i][j] = (f32x4){0.f, 0.f, 0.f, 0.f};

#pragma unroll 1
    for (int ks = 0; ks < KSTEPS; ++ks) {
        const int k0 = ks * 32;
        uint4 va[NUA], vb[NUB];
        // ---- A fetch ----
        if constexpr (ASRC == 0) {
#pragma unroll
            for (int u = 0; u < NUA; ++u) va[u] = *(const uint4*)(gApBf[u] + k0);
        } else if constexpr (ASRC == 1) {
            float4 f0 = *(const float4*)(gApF + k0);
            float4 f1 = *(const float4*)(gApF + k0 + 4);
            float vv[8] = {f0.x, f0.y, f0.z, f0.w, f1.x, f1.y, f1.z, f1.w};
            union { unsigned short u[8]; uint4 q; } o;
#pragma unroll
            for (int q = 0; q < 8; ++q) o.u[q] = f2bf(vv[q] * scp[k0 + q]);
            va[0] = o.q;
        } else {   // ASRC 2
            union { unsigned short u[8]; uint4 q; } o;
            if (k0 < 512) {
                float4 f0 = *(const float4*)(gApF + k0);
                float4 f1 = *(const float4*)(gApF + k0 + 4);
                float vv[8] = {f0.x, f0.y, f0.z, f0.w, f1.x, f1.y, f1.z, f1.w};
#pragma unroll
                for (int q = 0; q < 8; ++q) o.u[q] = f2bf(vv[q] * scp[k0 + q]);
            } else {
                const int cn = ((rowT % NP) + arow) >> 5;
#pragma unroll
                for (int q = 0; q < 8; ++q) {
                    int gk = k0 + ag * 8 + q;
                    float v = (gk < 522 && (gk - 512) == cn)
                                  ? ascale[(size_t)m * 522 + gk] : 0.f;
                    o.u[q] = f2bf(v);
                }
            }
            va[0] = o.q;
        }
        // ---- B fetch ----
        if constexpr (BSRC == 0) {
#pragma unroll
            for (int u = 0; u < NUB; ++u) vb[u] = *(const uint4*)(gBpBf[u] + k0);
        } else {
            union { unsigned short u[8]; uint4 q; } o;
#pragma unroll
            for (int q = 0; q < 8; ++q) {
                int gk = k0 + bkg * 8 + q;
                float v = 0.f;
                if (!BCHK || gk < KREALB)
                    v = Bf32[(size_t)gk * 512 + colT + bcol];
                o.u[q] = f2bf(v);
            }
            vb[0] = o.q;
        }
        __syncthreads();
#pragma unroll
        for (int u = 0; u < NUA; ++u) *(uint4*)(As + stA[u]) = va[u];
#pragma unroll
        for (int u = 0; u < NUB; ++u) *(uint4*)(Bs + stB[u]) = vb[u];
        __syncthreads();
        bf16x8 af[I], bfv[J];
#pragma unroll
        for (int i = 0; i < I; ++i) af[i] = *(const bf16x8*)(As + offA[i]);
#pragma unroll
        for (int j = 0; j < J; ++j) bfv[j] = *(const bf16x8*)(Bs + offB[j]);
#pragma unroll
        for (int i = 0; i < I; ++i)
#pragma unroll
            for (int j = 0; j < J; ++j)
                acc[i][j] = __builtin_amdgcn_mfma_f32_16x16x32_bf16(
                    af[i], bfv[j], acc[i][j], 0, 0, 0);
    }

    if constexpr (EPI == 0) {
#pragma unroll
        for (int j = 0; j < J; ++j) {
            const int col = colT + wc * (J * 16) + j * 16 + l15;
            const float sv = s[(size_t)m * NCOLS + col];
            const float bv = bias[(size_t)m * NCOLS + col];
            const float rv = auxr[(size_t)m * NCOLS + col];
#pragma unroll
            for (int i = 0; i < I; ++i)
#pragma unroll
                for (int ir = 0; ir < 4; ++ir) {
                    const int row = rowT + wr * (I * 16) + i * 16 + l4 * 4 + ir;
                    float v = fmaxf(acc[i][j][ir] * sv + bv, 0.f) * rv;
                    ((unsigned short*)outv)[(size_t)row * NCOLS + col] = f2bf(v);
                }
        }
    } else if constexpr (EPI == 1) {
        static_assert(I == 2, "EPI1 needs 32-row waves");
        const int grow = rowT + wr * 32;             // one class group per wave
        const int mcm = grow / NP;
        const int c = (grow % NP) / KK;
        const int mc = mcm * CC + c;
        float sq = 0.f;
#pragma unroll
        for (int j = 0; j < J; ++j) {
            const int col = colT + wc * (J * 16) + j * 16 + l15;
            const float sv = s[(size_t)mcm * NCOLS + col];
            const float bv = bias[(size_t)mcm * NCOLS + col];
            float cs = 0.f;
#pragma unroll
            for (int i = 0; i < I; ++i)
#pragma unroll
                for (int ir = 0; ir < 4; ++ir) {
                    float v = acc[i][j][ir] * sv + bv;
                    cs += v;
                    sq += v * v;
                }
            cs += __shfl_xor(cs, 16, 64);
            cs += __shfl_xor(cs, 32, 64);
            if (l4 == 0) ((float*)outv)[(size_t)mc * FF + col] = cs;
        }
#pragma unroll
        for (int off = 1; off < 64; off <<= 1) sq += __shfl_xor(sq, off, 64);
        if (lane == 0) atomicAdd(&auxw[mc], sq);
    } else {
        static_assert(I == 2 && J == 4, "EPI2 expects 64x128 tile");
        const int cb = colT / FF;                    // class of this col tile
        float sv[J], pv[J];
#pragma unroll
        for (int j = 0; j < J; ++j) {
            const int col = colT + wc * (J * 16) + j * 16 + l15;   // (c,f) order
            sv[j] = s[(size_t)m * NCOLS + (col & 511) * 10 + (col >> 9)];
            pv[j] = bias[(size_t)m * NCOLS + col];   // psum, (c,f)-ordered
        }
        float* dst = (float*)outv;
#pragma unroll
        for (int i = 0; i < I; ++i)
#pragma unroll
            for (int ir = 0; ir < 4; ++ir) {
                const int row = rowT + wr * (I * 16) + i * 16 + l4 * 4 + ir;
                float znv = 0.f, crv = 0.f;
#pragma unroll
                for (int j = 0; j < J; ++j) {
                    float v = acc[i][j][ir] * sv[j];
                    znv += v * v;
                    crv += v * pv[j];
                }
#pragma unroll
                for (int off = 1; off < 16; off <<= 1) {
                    znv += __shfl_xor(znv, off, 64);
                    crv += __shfl_xor(crv, off, 64);
                }
                if (l15 == 0) {
                    float* dp = dst + ((size_t)row * CC + cb) * 2;
                    atomicAdd(dp + 0, znv);
                    atomicAdd(dp + 1, crv);
                }
            }
    }
}

// =================== K1: fc1 GEMM + W_lw transpose + zeroing ===================
__global__ __launch_bounds__(256) void k_phase1(
    const float* __restrict__ noise, const float* __restrict__ r1,
    const float* __restrict__ W1, const float* __restrict__ s1,
    const float* __restrict__ b1, const float* __restrict__ r2,
    const float* __restrict__ W_lw,
    unsigned short* __restrict__ A2, unsigned short* __restrict__ Wlwt,
    float* __restrict__ dist, float* __restrict__ pn,
    unsigned int* __restrict__ ticket)
{
    __shared__ __align__(16) unsigned short smem[8192];
    const int b = blockIdx.x;
    const int t = threadIdx.x;
    if (b < 160) {
        // fc1: A = noise*r1 (+onehot), B = W1 [522][512] f32 direct
        gemm_tile<0, 2, 1, 2, 2, 17, 522, NP, HH>(
            b % 8, b / 8, nullptr, noise, r1, nullptr, W1,
            s1, b1, r2, (void*)A2, nullptr, smem);
    } else if (b < 800) {
        // W_lw [512][5120] f32 -> Wlwt[(c,f)][512] bf16 (col remap (f,c)->(c,f))
        unsigned short (*T)[65] = (unsigned short (*)[65])smem;
        const int bb = b - 160;
        const int n0 = (bb % 80) * 64, k0 = (bb / 80) * 64;
#pragma unroll
        for (int p = 0; p < 4; ++p) {
            int kk = (t >> 4) + p * 16;
            int nn = (t & 15) * 4;
            float4 v = *(const float4*)(W_lw + (size_t)(k0 + kk) * OUTW + n0 + nn);
            T[nn + 0][kk] = f2bf(v.x);
            T[nn + 1][kk] = f2bf(v.y);
            T[nn + 2][kk] = f2bf(v.z);
            T[nn + 3][kk] = f2bf(v.w);
        }
        __syncthreads();
#pragma unroll
        for (int p = 0; p < 2; ++p) {
            int n = (t >> 3) + p * 32;
            int kg = t & 7;
            union { unsigned short u[8]; uint4 v; } o;
#pragma unroll
            for (int q = 0; q < 8; ++q) o.u[q] = T[n][kg * 8 + q];
            int gn = n0 + n;
            int dr = (gn % 10) * 512 + gn / 10;      // (f,c) -> (c,f)
            *(uint4*)(Wlwt + (size_t)dr * 512 + k0 + kg * 8) = o.v;
        }
    } else {
        for (int id = t; id < 10240; id += 256) dist[id] = 0.f;
        if (t < 40) pn[t] = 0.f;
        if (t == 0) *ticket = 0u;
    }
}

// =================== K2: fc2 GEMM + fused psum/pn ===================
__global__ __launch_bounds__(256) void k_phase2(
    const unsigned short* __restrict__ A2, const float* __restrict__ W2,
    const float* __restrict__ s2, const float* __restrict__ b2,
    float* __restrict__ psum, float* __restrict__ pn)
{
    __shared__ __align__(16) unsigned short smem[8192];
    gemm_tile<1, 0, 1, 2, 2, 16, 512, NP, FF>(
        blockIdx.x, blockIdx.y, A2, nullptr, nullptr, nullptr, W2,
        s2, b2, nullptr, (void*)psum, pn, smem);
}

// =================== K3: z GEMM + fused zn/cr + tail-block exp ===================
__global__ __launch_bounds__(256) void k_phase3(
    const float* __restrict__ x, const float* __restrict__ r_lw,
    const unsigned short* __restrict__ Wlwt, const float* __restrict__ s_lw,
    const float* __restrict__ psum, float* __restrict__ dist,
    const float* __restrict__ pn, unsigned int* __restrict__ ticket,
    float* __restrict__ out)
{
    __shared__ __align__(16) unsigned short smem[8192];
    gemm_tile<2, 1, 0, 2, 4, 16, 512, BB, OUTW>(
        blockIdx.x, blockIdx.y, nullptr, x, r_lw, Wlwt, nullptr,
        s_lw, psum, nullptr, (void*)dist, nullptr, smem);

    __shared__ unsigned winner;
    __syncthreads();
    if (threadIdx.x == 0) {
        __threadfence();
        unsigned old = __hip_atomic_fetch_add(ticket, 1u, __ATOMIC_ACQ_REL,
                                              __HIP_MEMORY_SCOPE_AGENT);
        winner = (old == 319u) ? 1u : 0u;
    }
    __syncthreads();
    if (winner) {
        const float inv = 1.f / (2.f * (float)KK * (float)FF);
        for (int id = threadIdx.x; id < 5120; id += 256) {
            float zn = __hip_atomic_load(&dist[id * 2], __ATOMIC_RELAXED,
                                         __HIP_MEMORY_SCOPE_AGENT);
            float cr = __hip_atomic_load(&dist[id * 2 + 1], __ATOMIC_RELAXED,
                                         __HIP_MEMORY_SCOPE_AGENT);
            int c = id % 10, mm = (id / 10) >> 7;
            out[id] = expf(-((float)KK * zn - 2.f * cr + pn[mm * 10 + c]) * inv);
        }
    }
}

extern "C" void kernel_launch(void* const* d_in, const int* in_sizes, int n_in,
                              void* d_out, int out_size, void* d_ws, size_t ws_size,
                              hipStream_t stream) {
    const float* x     = (const float*)d_in[0];
    const float* noise = (const float*)d_in[1];
    const float* W_lw  = (const float*)d_in[2];
    const float* r_lw  = (const float*)d_in[3];
    const float* s_lw  = (const float*)d_in[4];
    const float* W1    = (const float*)d_in[5];
    const float* r1    = (const float*)d_in[6];
    const float* s1    = (const float*)d_in[7];
    const float* b1    = (const float*)d_in[8];
    const float* W2    = (const float*)d_in[9];
    const float* r2    = (const float*)d_in[10];
    const float* s2    = (const float*)d_in[11];
    const float* b2    = (const float*)d_in[12];
    float* out = (float*)d_out;

    char* base = (char*)d_ws;
    float* dist          = (float*)(base + 0);          // 40,960 B
    float* pn            = (float*)(base + 40960);      // 160 B (pad)
    unsigned int* ticket = (unsigned int*)(base + 41216);
    float* psum          = (float*)(base + 41472);      // 81,920 B
    unsigned short* A2   = (unsigned short*)(base + 123392);   // 1,310,720 B
    unsigned short* Wlwt = (unsigned short*)(base + 1434112);  // 5,242,880 B

    k_phase1<<<801, 256, 0, stream>>>(noise, r1, W1, s1, b1, r2, W_lw,
                                      A2, Wlwt, dist, pn, ticket);
    k_phase2<<<dim3(8, 20), 256, 0, stream>>>(A2, W2, s2, b2, psum, pn);
    k_phase3<<<dim3(40, 8), 256, 0, stream>>>(x, r_lw, Wlwt, s_lw, psum,
                                              dist, pn, ticket, out);
}

// Round 6
// 56.156 us; speedup vs baseline: 8.7861x; 1.6072x over previous
//
#include <hip/hip_runtime.h>
#include <math.h>

#define MM 4
#define BB 128
#define CC 10
#define KK 32
#define FF 512
#define HH 512
#define NP 320            // C*K rows per model
#define OUTW 5120         // F*C

using bf16x8 = __attribute__((ext_vector_type(8))) short;
using f32x4  = __attribute__((ext_vector_type(4))) float;

__device__ __forceinline__ unsigned short f2bf(float f) {
    unsigned int u = __float_as_uint(f);
    u += 0x7FFFu + ((u >> 16) & 1u);          // round-to-nearest-even
    return (unsigned short)(u >> 16);
}

// ---------------- unified pipelined MFMA GEMM tile ----------------
// Wave layout WR x WC; per-wave fragment repeat I x J. TR=WR*I*16, TC=WC*J*16.
// Double-buffered LDS, fetch(k+1) in regs before MFMA(k), one barrier/step.
// EPI 0: outv(u16) = bf16( relu(acc*s + bias) * auxr )           (fc1 -> A2)
// EPI 1: psum write + pn_part slot write (WR==1, TR==32)         (fc2)
// EPI 2: zn/cr slot writes into dist_part (WR==2,WC==2,I==2,J==2)(z-GEMM)
// ASRC 0: bf16 A[row][512]
// ASRC 2: f32 noise[row%NP][512]*r1, onehot tail steps k>=512
// BSRC 0: bf16 Bt[col][512]
// BSRC 1: f32 W[k][TCOLS] k-major gather (TC==64)
template<int EPI, int ASRC, int BSRC, int WR, int WC, int I, int J,
         int KSTEPS, int KREALB, int RPM, int NCOLS>
__device__ __forceinline__ void gemm_tile(
    const int bx, const int by,
    const unsigned short* __restrict__ Abf, const float* __restrict__ Af32,
    const float* __restrict__ ascale,
    const unsigned short* __restrict__ Btbf, const float* __restrict__ Bf32,
    const float* __restrict__ s, const float* __restrict__ bias,
    const float* __restrict__ auxr, void* __restrict__ outv,
    float* __restrict__ auxw, unsigned short* smem)
{
    constexpr int TR = WR * I * 16;
    constexpr int TC = WC * J * 16;
    constexpr int BUFE = (TR + TC) * 32;         // elems per (A|B) buffer
    const int t = threadIdx.x;
    const int lane = t & 63;
    const int w = t >> 6;
    const int wr = w / WC, wc = w % WC;
    const int l15 = lane & 15, l4 = lane >> 4;
    const int rowT = by * TR, colT = bx * TC;
    const int m = rowT / RPM;

    // ---- A staging setup (1 uint4 unit/thread; guard if TR<64) ----
    constexpr bool AGUARD = (TR * 4 < 256);
    const bool aact = !AGUARD || (t < TR * 4);
    const int asrow = t >> 2, ag = t & 3;
    const int stA = asrow * 32 + ((ag ^ ((asrow >> 1) & 3)) * 8);
    const unsigned short* gA = nullptr;
    const float* gAf = nullptr;
    const float* scp = nullptr;
    int cn = 0;
    if constexpr (ASRC == 0) {
        if (aact) gA = Abf + (size_t)(rowT + asrow) * 512 + ag * 8;
    } else {
        gAf = Af32 + (size_t)((rowT % NP) + asrow) * 512 + ag * 8;
        scp = ascale + (size_t)m * 522 + ag * 8;
        cn = ((rowT % NP) + asrow) >> 5;
    }
    // ---- B staging setup ----
    const int bsrow = t >> 2, bg = t & 3;        // BSRC0
    const int stB0 = bsrow * 32 + ((bg ^ ((bsrow >> 1) & 3)) * 8);
    const int bcol = t & 63, bkg = t >> 6;       // BSRC1
    const int stB1 = bcol * 32 + ((bkg ^ ((bcol >> 1) & 3)) * 8);
    const unsigned short* gB = nullptr;
    if constexpr (BSRC == 0)
        gB = Btbf + (size_t)(colT + bsrow) * 512 + bg * 8;

    int offA[I], offB[J];
#pragma unroll
    for (int i = 0; i < I; ++i) {
        int rA = wr * (I * 16) + i * 16 + l15;
        offA[i] = rA * 32 + ((l4 ^ ((rA >> 1) & 3)) * 8);
    }
#pragma unroll
    for (int j = 0; j < J; ++j) {
        int rB = wc * (J * 16) + j * 16 + l15;
        offB[j] = rB * 32 + ((l4 ^ ((rB >> 1) & 3)) * 8);
    }

    f32x4 acc[I][J];
#pragma unroll
    for (int i = 0; i < I; ++i)
#pragma unroll
        for (int j = 0; j < J; ++j) acc[i][j] = (f32x4){0.f, 0.f, 0.f, 0.f};

    // register staging state
    uint4 ra, rb;
    float4 nf0, nf1, ns0, ns1;
    float rbf[8];

#define FETCH(KS)                                                              \
    {                                                                          \
        const int k0 = (KS) * 32;                                              \
        if constexpr (ASRC == 0) {                                             \
            if (aact) ra = *(const uint4*)(gA + k0);                           \
        } else {                                                               \
            if (k0 < 512) {                                                    \
                nf0 = *(const float4*)(gAf + k0);                              \
                nf1 = *(const float4*)(gAf + k0 + 4);                          \
                ns0 = *(const float4*)(scp + k0);                              \
                ns1 = *(const float4*)(scp + k0 + 4);                          \
            }                                                                  \
        }                                                                      \
        if constexpr (BSRC == 0) {                                             \
            rb = *(const uint4*)(gB + k0);                                     \
        } else {                                                               \
            _Pragma("unroll")                                                  \
            for (int q = 0; q < 8; ++q) {                                      \
                int gk = k0 + bkg * 8 + q;                                     \
                rbf[q] = (gk < KREALB)                                         \
                    ? Bf32[(size_t)gk * NCOLS + colT + bcol] : 0.f;            \
            }                                                                  \
        }                                                                      \
    }

#define WRITE(KS, BUF)                                                         \
    {                                                                          \
        const int k0 = (KS) * 32;                                              \
        unsigned short* As_ = smem + (BUF) * BUFE;                             \
        unsigned short* Bs_ = As_ + TR * 32;                                   \
        if constexpr (ASRC == 0) {                                             \
            if (aact) *(uint4*)(As_ + stA) = ra;                               \
        } else {                                                               \
            union { unsigned short u[8]; uint4 q; } o;                         \
            if (k0 < 512) {                                                    \
                float vv[8] = {nf0.x, nf0.y, nf0.z, nf0.w,                     \
                               nf1.x, nf1.y, nf1.z, nf1.w};                    \
                float ss[8] = {ns0.x, ns0.y, ns0.z, ns0.w,                     \
                               ns1.x, ns1.y, ns1.z, ns1.w};                    \
                _Pragma("unroll")                                              \
                for (int q = 0; q < 8; ++q) o.u[q] = f2bf(vv[q] * ss[q]);      \
            } else {                                                           \
                _Pragma("unroll")                                              \
                for (int q = 0; q < 8; ++q) {                                  \
                    int gk = k0 + ag * 8 + q;                                  \
                    float v = (gk < 522 && (gk - 512) == cn)                   \
                        ? ascale[(size_t)m * 522 + gk] : 0.f;                  \
                    o.u[q] = f2bf(v);                                          \
                }                                                              \
            }                                                                  \
            *(uint4*)(As_ + stA) = o.q;                                        \
        }                                                                      \
        if constexpr (BSRC == 0) {                                             \
            *(uint4*)(Bs_ + stB0) = rb;                                        \
        } else {                                                               \
            union { unsigned short u[8]; uint4 q; } o;                         \
            _Pragma("unroll")                                                  \
            for (int q = 0; q < 8; ++q) o.u[q] = f2bf(rbf[q]);                 \
            *(uint4*)(Bs_ + stB1) = o.q;                                       \
        }                                                                      \
    }

    // prologue
    FETCH(0);
    WRITE(0, 0);
    __syncthreads();

#pragma unroll 1
    for (int ks = 0; ks < KSTEPS; ++ks) {
        const int cur = ks & 1;
        if (ks + 1 < KSTEPS) FETCH(ks + 1);
        const unsigned short* As_ = smem + cur * BUFE;
        const unsigned short* Bs_ = As_ + TR * 32;
        bf16x8 af[I], bfv[J];
#pragma unroll
        for (int i = 0; i < I; ++i) af[i] = *(const bf16x8*)(As_ + offA[i]);
#pragma unroll
        for (int j = 0; j < J; ++j) bfv[j] = *(const bf16x8*)(Bs_ + offB[j]);
#pragma unroll
        for (int i = 0; i < I; ++i)
#pragma unroll
            for (int j = 0; j < J; ++j)
                acc[i][j] = __builtin_amdgcn_mfma_f32_16x16x32_bf16(
                    af[i], bfv[j], acc[i][j], 0, 0, 0);
        if (ks + 1 < KSTEPS) {
            WRITE(ks + 1, cur ^ 1);
            __syncthreads();
        }
    }
#undef FETCH
#undef WRITE

    if constexpr (EPI == 0) {
#pragma unroll
        for (int j = 0; j < J; ++j) {
            const int col = colT + wc * (J * 16) + j * 16 + l15;
            const float sv = s[(size_t)m * NCOLS + col];
            const float bv = bias[(size_t)m * NCOLS + col];
            const float rv = auxr[(size_t)m * NCOLS + col];
#pragma unroll
            for (int i = 0; i < I; ++i)
#pragma unroll
                for (int ir = 0; ir < 4; ++ir) {
                    const int row = rowT + wr * (I * 16) + i * 16 + l4 * 4 + ir;
                    float v = fmaxf(acc[i][j][ir] * sv + bv, 0.f) * rv;
                    ((unsigned short*)outv)[(size_t)row * NCOLS + col] = f2bf(v);
                }
        }
    } else if constexpr (EPI == 1) {
        // TR==32: block rows = one (m,c) class group; all 4 waves same group
        static_assert(WR == 1 && I == 2 && J == 1, "EPI1 geometry");
        const int mq = rowT / NP;
        const int c = (rowT % NP) / KK;
        const int mc = mq * CC + c;
        const int col = colT + wc * 16 + l15;
        const float sv = s[(size_t)mq * NCOLS + col];
        const float bv = bias[(size_t)mq * NCOLS + col];
        float cs = 0.f, sq = 0.f;
#pragma unroll
        for (int i = 0; i < I; ++i)
#pragma unroll
            for (int ir = 0; ir < 4; ++ir) {
                float v = acc[i][0][ir] * sv + bv;
                cs += v;
                sq += v * v;
            }
        cs += __shfl_xor(cs, 16, 64);
        cs += __shfl_xor(cs, 32, 64);
        if (l4 == 0) ((float*)outv)[(size_t)mc * FF + col] = cs;
#pragma unroll
        for (int off = 1; off < 64; off <<= 1) sq += __shfl_xor(sq, off, 64);
        if (lane == 0) auxw[mc * 32 + bx * 4 + w] = sq;
    } else {
        // EPI 2: dist_part[row][c][slot][2], slot = (bx&7)*2 + wc
        static_assert(WR == 2 && WC == 2 && I == 2 && J == 2, "EPI2 geometry");
        const int cb = colT >> 9;
        const int slot = ((bx & 7) << 1) | wc;
        float sv[J], pv[J];
#pragma unroll
        for (int j = 0; j < J; ++j) {
            const int col = colT + wc * (J * 16) + j * 16 + l15;   // (c,f) order
            sv[j] = s[(size_t)m * NCOLS + (col & 511) * 10 + (col >> 9)];
            pv[j] = bias[(size_t)m * NCOLS + col];                 // psum
        }
        float* dst = (float*)outv;
#pragma unroll
        for (int i = 0; i < I; ++i)
#pragma unroll
            for (int ir = 0; ir < 4; ++ir) {
                const int row = rowT + wr * (I * 16) + i * 16 + l4 * 4 + ir;
                float znv = 0.f, crv = 0.f;
#pragma unroll
                for (int j = 0; j < J; ++j) {
                    float v = acc[i][j][ir] * sv[j];
                    znv += v * v;
                    crv += v * pv[j];
                }
#pragma unroll
                for (int off = 1; off < 16; off <<= 1) {
                    znv += __shfl_xor(znv, off, 64);
                    crv += __shfl_xor(crv, off, 64);
                }
                if (l15 == 0) {
                    float2 o = {znv, crv};
                    *(float2*)(dst + ((size_t)(row * CC + cb) * 16 + slot) * 2) = o;
                }
            }
    }
}

// =================== K1: fc1 GEMM + W_lw transpose + xr build ===================
__global__ __launch_bounds__(256) void k_phase1(
    const float* __restrict__ noise, const float* __restrict__ r1,
    const float* __restrict__ W1, const float* __restrict__ s1,
    const float* __restrict__ b1, const float* __restrict__ r2,
    const float* __restrict__ W_lw, const float* __restrict__ x,
    const float* __restrict__ r_lw,
    unsigned short* __restrict__ A2, unsigned short* __restrict__ Wlwt,
    unsigned short* __restrict__ xr)
{
    __shared__ __align__(16) unsigned short smem[8192];  // 16 KiB
    const int b = blockIdx.x;
    const int t = threadIdx.x;
    if (b < 160) {
        // fc1: A = noise*r1 (+onehot tail), B = W1 [522][512] f32 direct
        gemm_tile<0, 2, 1, 2, 2, 2, 2, 17, 522, NP, HH>(
            b % 8, b / 8, nullptr, noise, r1, nullptr, W1,
            s1, b1, r2, (void*)A2, nullptr, smem);
    } else if (b < 800) {
        // W_lw [512][5120] f32 -> Wlwt[(c,f)][512] bf16 (col remap (f,c)->(c,f))
        unsigned short (*T)[65] = (unsigned short (*)[65])smem;
        const int bb = b - 160;
        const int n0 = (bb % 80) * 64, k0 = (bb / 80) * 64;
#pragma unroll
        for (int p = 0; p < 4; ++p) {
            int kk = (t >> 4) + p * 16;
            int nn = (t & 15) * 4;
            float4 v = *(const float4*)(W_lw + (size_t)(k0 + kk) * OUTW + n0 + nn);
            T[nn + 0][kk] = f2bf(v.x);
            T[nn + 1][kk] = f2bf(v.y);
            T[nn + 2][kk] = f2bf(v.z);
            T[nn + 3][kk] = f2bf(v.w);
        }
        __syncthreads();
#pragma unroll
        for (int p = 0; p < 2; ++p) {
            int n = (t >> 3) + p * 32;
            int kg = t & 7;
            union { unsigned short u[8]; uint4 v; } o;
#pragma unroll
            for (int q = 0; q < 8; ++q) o.u[q] = T[n][kg * 8 + q];
            int gn = n0 + n;
            int dr = (gn % 10) * 512 + gn / 10;      // (f,c) -> (c,f)
            *(uint4*)(Wlwt + (size_t)dr * 512 + k0 + kg * 8) = o.v;
        }
    } else {
        // xr [512][512] bf16 = x * r_lw
        const int id = (b - 800) * 256 + t;          // 32768 exact
        const int row = id >> 6, g = id & 63;
        const int mq = row >> 7;
        const float* xp = x + (size_t)row * 512 + g * 8;
        const float* rp = r_lw + (size_t)mq * 512 + g * 8;
        union { unsigned short u[8]; uint4 v; } o;
#pragma unroll
        for (int q = 0; q < 8; ++q) o.u[q] = f2bf(xp[q] * rp[q]);
        *(uint4*)(xr + (size_t)row * 512 + g * 8) = o.v;
    }
}

// =================== K2: fc2 GEMM + fused psum/pn_part ===================
__global__ __launch_bounds__(256) void k_phase2(
    const unsigned short* __restrict__ A2, const float* __restrict__ W2,
    const float* __restrict__ s2, const float* __restrict__ b2,
    float* __restrict__ psum, float* __restrict__ pn_part)
{
    __shared__ __align__(16) unsigned short smem[6144];  // 12 KiB
    gemm_tile<1, 0, 1, 1, 4, 2, 1, 16, 512, NP, FF>(
        blockIdx.x, blockIdx.y, A2, nullptr, nullptr, nullptr, W2,
        s2, b2, nullptr, (void*)psum, pn_part, smem);
}

// =================== K3: z GEMM + fused zn/cr slot writes ===================
__global__ __launch_bounds__(256) void k_phase3(
    const unsigned short* __restrict__ xr, const unsigned short* __restrict__ Wlwt,
    const float* __restrict__ s_lw, const float* __restrict__ psum,
    float* __restrict__ dist_part)
{
    __shared__ __align__(16) unsigned short smem[8192];  // 16 KiB
    gemm_tile<2, 0, 0, 2, 2, 2, 2, 16, 512, BB, OUTW>(
        blockIdx.x, blockIdx.y, xr, nullptr, nullptr, Wlwt, nullptr,
        s_lw, psum, nullptr, (void*)dist_part, nullptr, smem);
}

// =================== K4: reduce partials + exp ===================
__global__ __launch_bounds__(256) void k_out(
    const float* __restrict__ dist_part, const float* __restrict__ pn_part,
    float* __restrict__ out)
{
    const int id = blockIdx.x * 256 + threadIdx.x;   // 5120 exact
    const int c = id % 10;
    const int mb = id / 10;
    const int mc = (mb >> 7) * 10 + c;
    const float* dp = dist_part + (size_t)id * 32;   // 16 slots x {zn,cr}
    float zn = 0.f, cr = 0.f;
#pragma unroll
    for (int q = 0; q < 16; ++q) {
        zn += dp[q * 2];
        cr += dp[q * 2 + 1];
    }
    float pnv = 0.f;
#pragma unroll
    for (int q = 0; q < 32; ++q) pnv += pn_part[mc * 32 + q];
    const float inv = 1.f / (2.f * (float)KK * (float)FF);
    out[id] = expf(-((float)KK * zn - 2.f * cr + pnv) * inv);
}

extern "C" void kernel_launch(void* const* d_in, const int* in_sizes, int n_in,
                              void* d_out, int out_size, void* d_ws, size_t ws_size,
                              hipStream_t stream) {
    const float* x     = (const float*)d_in[0];
    const float* noise = (const float*)d_in[1];
    const float* W_lw  = (const float*)d_in[2];
    const float* r_lw  = (const float*)d_in[3];
    const float* s_lw  = (const float*)d_in[4];
    const float* W1    = (const float*)d_in[5];
    const float* r1    = (const float*)d_in[6];
    const float* s1    = (const float*)d_in[7];
    const float* b1    = (const float*)d_in[8];
    const float* W2    = (const float*)d_in[9];
    const float* r2    = (const float*)d_in[10];
    const float* s2    = (const float*)d_in[11];
    const float* b2    = (const float*)d_in[12];
    float* out = (float*)d_out;

    char* base = (char*)d_ws;
    float* psum          = (float*)(base + 0);                 //    81,920 B
    float* pn_part       = (float*)(base + 81920);             //     5,120 B
    float* dist_part     = (float*)(base + 87040);             //   655,360 B
    unsigned short* A2   = (unsigned short*)(base + 742400);   // 1,310,720 B
    unsigned short* xr   = (unsigned short*)(base + 2053120);  //   524,288 B
    unsigned short* Wlwt = (unsigned short*)(base + 2577408);  // 5,242,880 B

    k_phase1<<<928, 256, 0, stream>>>(noise, r1, W1, s1, b1, r2, W_lw, x, r_lw,
                                      A2, Wlwt, xr);
    k_phase2<<<dim3(8, 40), 256, 0, stream>>>(A2, W2, s2, b2, psum, pn_part);
    k_phase3<<<dim3(80, 8), 256, 0, stream>>>(xr, Wlwt, s_lw, psum, dist_part);
    k_out<<<20, 256, 0, stream>>>(dist_part, pn_part, out);
}